// Round 15
// baseline (6601.750 us; speedup 1.0000x reference)
//
#include <hip/hip_runtime.h>
#include <stdint.h>

#define BS 8192
#define NDIM 1024
#define T_STEPS 100
#define CUE_T 10
#define BK 64
#define NKT (NDIM / BK)
#define MASK_CHUNK 20
#define SLOTS_PER_STEP (512 * 256)   // u64 masks per step

typedef __attribute__((ext_vector_type(8))) short bf16x8;
typedef __attribute__((ext_vector_type(16))) float f32x16;

// ---------------- bf16 helpers (RNE, XLA-compatible) ----------------
__device__ inline uint16_t f32_to_bf16(float f) {
    uint32_t u = __float_as_uint(f);
    uint32_t r = u + 0x7fffu + ((u >> 16) & 1u);
    return (uint16_t)(r >> 16);
}
__device__ inline float bf16_to_f32(uint16_t h) {
    return __uint_as_float(((uint32_t)h) << 16);
}

// ---------------- threefry2x32 (JAX-exact core) ----------------
__host__ __device__ inline uint32_t rotl32_(uint32_t x, uint32_t r) {
    return (x << r) | (x >> (32u - r));
}

__host__ __device__ inline void tf2x32(uint32_t k0, uint32_t k1,
                                       uint32_t x0, uint32_t x1,
                                       uint32_t &o0, uint32_t &o1) {
    uint32_t ks2 = k0 ^ k1 ^ 0x1BD11BDAu;
    x0 += k0; x1 += k1;
#define TF_R4(a,b,c,d) \
    x0 += x1; x1 = rotl32_(x1,(a)); x1 ^= x0; \
    x0 += x1; x1 = rotl32_(x1,(b)); x1 ^= x0; \
    x0 += x1; x1 = rotl32_(x1,(c)); x1 ^= x0; \
    x0 += x1; x1 = rotl32_(x1,(d)); x1 ^= x0;
    TF_R4(13,15,26,6)  x0 += k1;  x1 += ks2 + 1u;
    TF_R4(17,29,16,24) x0 += ks2; x1 += k0 + 2u;
    TF_R4(13,15,26,6)  x0 += k0;  x1 += k1 + 3u;
    TF_R4(17,29,16,24) x0 += k1;  x1 += ks2 + 4u;
    TF_R4(13,15,26,6)  x0 += ks2; x1 += k0 + 5u;
#undef TF_R4
    o0 = x0; o1 = x1;
}

// 4-wide interleaved threefry: 4 independent chains round-interleaved for ILP.
// counters (0, idx[i]); returns XOR-folded bits[i] = o0^o1 (JAX partitionable).
__device__ __forceinline__ void tf2x32_x4_fold(uint32_t k0, uint32_t k1,
                                               const uint32_t idx[4],
                                               uint32_t bits[4]) {
    uint32_t ks2 = k0 ^ k1 ^ 0x1BD11BDAu;
    uint32_t x0[4], x1[4];
    #pragma unroll
    for (int i = 0; i < 4; ++i) { x0[i] = k0; x1[i] = idx[i] + k1; }
#define TF4_R(rot) \
    _Pragma("unroll") \
    for (int i = 0; i < 4; ++i) { \
        x0[i] += x1[i]; x1[i] = rotl32_(x1[i], (rot)); x1[i] ^= x0[i]; }
#define TF4_K(a0, a1) \
    _Pragma("unroll") \
    for (int i = 0; i < 4; ++i) { x0[i] += (a0); x1[i] += (a1); }
    TF4_R(13) TF4_R(15) TF4_R(26) TF4_R(6)  TF4_K(k1, ks2 + 1u)
    TF4_R(17) TF4_R(29) TF4_R(16) TF4_R(24) TF4_K(ks2, k0 + 2u)
    TF4_R(13) TF4_R(15) TF4_R(26) TF4_R(6)  TF4_K(k0, k1 + 3u)
    TF4_R(17) TF4_R(29) TF4_R(16) TF4_R(24) TF4_K(k1, ks2 + 4u)
    TF4_R(13) TF4_R(15) TF4_R(26) TF4_R(6)  TF4_K(ks2, k0 + 5u)
#undef TF4_R
#undef TF4_K
    #pragma unroll
    for (int i = 0; i < 4; ++i) bits[i] = x0[i] ^ x1[i];
}

// fast sigmoid: v_exp_f32 + v_rcp_f32 (rel err ~1e-6, invisible under bf16)
__device__ inline float sigmoidf_(float x) {
    float e = __expf(-x);
    return __builtin_amdgcn_rcpf(1.0f + e);
}

// ---------------- async global->LDS, 16B per lane ----------------
__device__ __forceinline__ void gload16(const uint16_t* g, uint16_t* l) {
    __builtin_amdgcn_global_load_lds(
        (const __attribute__((address_space(1))) void*)g,
        (__attribute__((address_space(3))) void*)l, 16, 0, 0);
}

// ---------------- init: ec3bf = 0, ec5bf = bf16(ec5_init) ----------------
__global__ void init_kernel(const float* __restrict__ ec5_init,
                            uint16_t* __restrict__ ec3bf,
                            uint16_t* __restrict__ ec5bf, int n) {
    int i = blockIdx.x * blockDim.x + threadIdx.x;
    if (i < n) { ec3bf[i] = 0; ec5bf[i] = f32_to_bf16(ec5_init[i]); }
}

// ---------------- noise mask generation: all elements for MASK_CHUNK steps ----
// Pure-VALU, barrier-free, 4-wide ILP. Thread (bx, by, tid) computes the u64
// mask for gemm block lin=bx, thread tid, step tbase+by, bit-layout exactly as
// gemm2 consumes: bit e=i*8+j <-> element obase + i*16384 + j, where
// obase = (gx*128 + tid>>4)*1024 + gy*128 + (tid&15)*8, gx=lin&63, gy=lin>>6.
__global__ __launch_bounds__(256) void noise_kernel(uint64_t* __restrict__ maskbuf,
                                                    int tbase) {
    const int tid = threadIdx.x;
    const int lin = blockIdx.x;              // 0..511
    const int stp = tbase + blockIdx.y;      // step index
    uint32_t k0, k1;
    tf2x32(0u, 42u, 0u, (uint32_t)stp, k0, k1);   // fold_in(key(42), step)
    const int gx = lin & 63, gy = lin >> 6;
    const uint32_t obase = (uint32_t)(gx * 128 + (tid >> 4)) * NDIM
                         + (uint32_t)(gy * 128 + (tid & 15) * 8);
    uint64_t mask = 0;
    #pragma unroll
    for (int b = 0; b < 16; ++b) {           // batch b covers e = 4b..4b+3
        uint32_t idx[4], bits[4];
        const uint32_t base = obase + (uint32_t)((b >> 1) << 14)
                            + (uint32_t)((b & 1) << 2);
        #pragma unroll
        for (int u = 0; u < 4; ++u) idx[u] = base + u;
        tf2x32_x4_fold(k0, k1, idx, bits);
        #pragma unroll
        for (int u = 0; u < 4; ++u) {
            float uu = __uint_as_float((bits[u] >> 9) | 0x3f800000u) - 1.0f;
            mask |= (uint64_t)(uu < 0.004f ? 1u : 0u) << ((b << 2) + u);
        }
    }
    maskbuf[(size_t)blockIdx.y * SLOTS_PER_STEP + (size_t)lin * 256 + tid] = mask;
}

// ---------------- drive[t][c] = sum_j exp(-(cen_j - t)^2/50) * W[j][c] ----------------
__global__ __launch_bounds__(256) void drive_kernel(const float* __restrict__ W,
                                                    float* __restrict__ drive) {
    __shared__ float g[4][1024];
    const int t0 = blockIdx.x * 4;
    const int c = blockIdx.y * 64 + (threadIdx.x & 63);
    const int tt = threadIdx.x >> 6;
    const float stepf = 100.0f / 1023.0f;
    for (int i = threadIdx.x; i < 4096; i += 256) {
        int t_ = i >> 10, j = i & 1023;
        float d = stepf * (float)j - (float)(t0 + t_);
        g[t_][j] = expf(-(d * d) * 0.02f);
    }
    __syncthreads();
    float a = 0.f;
    for (int j = 0; j < 1024; ++j)
        a = fmaf(g[tt][j], W[(size_t)j * NDIM + c], a);
    drive[(size_t)(t0 + tt) * NDIM + c] = a;
}

// ---------------- Wt_bf16[n][k] = bf16(W[k][n]), runs once ----------------
__global__ __launch_bounds__(256) void wtrans_kernel(const float* __restrict__ W,
                                                     uint16_t* __restrict__ Wt) {
    __shared__ float tile[32][33];
    int k0 = blockIdx.x * 32, n0 = blockIdx.y * 32;
    int tx = threadIdx.x & 31, ty = threadIdx.x >> 5;
    #pragma unroll
    for (int i = 0; i < 32; i += 8)
        tile[ty + i][tx] = W[(size_t)(k0 + ty + i) * NDIM + n0 + tx];
    __syncthreads();
    #pragma unroll
    for (int i = 0; i < 32; i += 8)
        Wt[(size_t)(n0 + ty + i) * NDIM + k0 + tx] = f32_to_bf16(tile[tx][ty + i]);
}

// ---------------- 128x128 bf16 MFMA core (32x32x16, dbuf + counted vmcnt) ------
// 256 threads / 4 waves (2x2), 64x64/wave. LDS [128][BK=64] slot-XOR swizzled.
__device__ __forceinline__ void gemm_core(const uint16_t* __restrict__ A,
                                          const uint16_t* __restrict__ Bt,
                                          uint16_t* As, uint16_t* Bs,
                                          f32x16 acc[2][2]) {
    const int tid = threadIdx.x;
    const int wid = tid >> 6, lane = tid & 63;
    const int row0 = blockIdx.x * 128, col0 = blockIdx.y * 128;
    const int srow = lane >> 3;
    const int soff = ((lane & 7) ^ srow) * 8;
    const uint16_t* aS[4]; const uint16_t* bS[4];
    #pragma unroll
    for (int i = 0; i < 4; ++i) {
        int ch = wid * 4 + i;
        aS[i] = A  + (size_t)(row0 + ch * 8 + srow) * NDIM + soff;
        bS[i] = Bt + (size_t)(col0 + ch * 8 + srow) * NDIM + soff;
    }
    const int l31 = lane & 31, l5 = lane >> 5;
    const int wr = wid >> 1, wc = wid & 1;
    int aoff[2][4], boff[2][4];
    #pragma unroll
    for (int m = 0; m < 2; ++m)
        #pragma unroll
        for (int kk = 0; kk < 4; ++kk) {
            int ar = wr * 64 + m * 32 + l31;
            aoff[m][kk] = ar * BK + ((((kk << 1) | l5) ^ (ar & 7)) << 3);
            int br = wc * 64 + m * 32 + l31;
            boff[m][kk] = br * BK + ((((kk << 1) | l5) ^ (br & 7)) << 3);
        }

    #pragma unroll
    for (int i = 0; i < 4; ++i) {
        int ch = wid * 4 + i;
        gload16(aS[i], As + ch * 512);
        gload16(bS[i], Bs + ch * 512);
    }

    for (int kt = 0; kt < NKT; ++kt) {
        const int cur = kt & 1;
        if (kt + 1 < NKT) {
            const int nb = (cur ^ 1) * 8192;
            const int k0n = (kt + 1) * BK;
            #pragma unroll
            for (int i = 0; i < 4; ++i) {
                int ch = wid * 4 + i;
                gload16(aS[i] + k0n, As + nb + ch * 512);
                gload16(bS[i] + k0n, Bs + nb + ch * 512);
            }
            asm volatile("s_waitcnt vmcnt(8)" ::: "memory");
        } else {
            asm volatile("s_waitcnt vmcnt(0)" ::: "memory");
        }
        __builtin_amdgcn_s_barrier();
        __builtin_amdgcn_sched_barrier(0);
        const uint16_t* as = As + cur * 8192;
        const uint16_t* bs = Bs + cur * 8192;
        bf16x8 af[2][4], bfr[2][4];
        #pragma unroll
        for (int m = 0; m < 2; ++m)
            #pragma unroll
            for (int kk = 0; kk < 4; ++kk) {
                af[m][kk]  = *(const bf16x8*)&as[aoff[m][kk]];
                bfr[m][kk] = *(const bf16x8*)&bs[boff[m][kk]];
            }
        #pragma unroll
        for (int kk = 0; kk < 4; ++kk)
            #pragma unroll
            for (int m = 0; m < 2; ++m)
                #pragma unroll
                for (int n = 0; n < 2; ++n)
                    acc[m][n] = __builtin_amdgcn_mfma_f32_32x32x16_bf16(
                        af[m][kk], bfr[n][kk], acc[m][n], 0, 0, 0);
        __builtin_amdgcn_sched_barrier(0);
        __builtin_amdgcn_s_barrier();
    }
}

// Stage acc (MFMA C-layout) into LDS with chunk-XOR swizzle; coalesced re-read.
__device__ __forceinline__ void acc_to_lds(float* lacc, f32x16 acc[2][2]) {
    const int tid = threadIdx.x, wid = tid >> 6, lane = tid & 63;
    const int wr = wid >> 1, wc = wid & 1, l31 = lane & 31, l5 = lane >> 5;
    #pragma unroll
    for (int m = 0; m < 2; ++m)
        #pragma unroll
        for (int n = 0; n < 2; ++n) {
            int c = wc * 64 + n * 32 + l31;
            int chunk = c >> 2, cj = c & 3;
            #pragma unroll
            for (int e = 0; e < 16; ++e) {
                int r = wr * 64 + m * 32 + (e & 3) + ((e >> 2) << 3) + (l5 << 2);
                lacc[r * 128 + ((chunk ^ (r & 31)) << 2) + cj] = acc[m][n][e];
            }
        }
}

__device__ __forceinline__ void acc_read8(const float* lacc, int r, int a,
                                          float4 &v0, float4 &v1) {
    int rb = r & 31;
    v0 = *(const float4*)&lacc[r * 128 + ((((a << 1) | 0) ^ rb) << 2)];
    v1 = *(const float4*)&lacc[r * 128 + ((((a << 1) | 1) ^ rb) << 2)];
}

// gemm1: ca1 = relu(drv[c]*(1+sigmoid(ec3@W1)) - bias[c]) -> bf16 (+f32 at t=99)
__global__ __launch_bounds__(256, 2) void gemm1_kernel(
    const uint16_t* __restrict__ ec3bf, const uint16_t* __restrict__ W1t,
    const float* __restrict__ drv, const float* __restrict__ bias,
    uint16_t* __restrict__ ca1bf, float* __restrict__ ca1f, int writef32)
{
    __shared__ __align__(16) uint16_t SM[2][16384];
    uint16_t* As = SM[0];
    uint16_t* Bs = SM[1];
    f32x16 acc[2][2];
    #pragma unroll
    for (int m = 0; m < 2; ++m)
        #pragma unroll
        for (int n = 0; n < 2; ++n)
            acc[m][n] = (f32x16)(0.0f);
    gemm_core(ec3bf, W1t, As, Bs, acc);

    float* lacc = (float*)SM;
    acc_to_lds(lacc, acc);
    __syncthreads();

    const int tid = threadIdx.x;
    const int row0 = blockIdx.x * 128, col0 = blockIdx.y * 128;
    const int a = tid & 15;
    int gc = col0 + a * 8;
    float4 d0 = *(const float4*)&drv[gc];
    float4 d1 = *(const float4*)&drv[gc + 4];
    float4 b0 = *(const float4*)&bias[gc];
    float4 b1 = *(const float4*)&bias[gc + 4];
    #pragma unroll
    for (int i = 0; i < 8; ++i) {
        int r = (tid >> 4) + i * 16;
        float4 v0, v1;
        acc_read8(lacc, r, a, v0, v1);
        size_t off = (size_t)(row0 + r) * NDIM + gc;
        float vout[8];
        #pragma unroll
        for (int j = 0; j < 8; ++j) {
            float accv = j < 4 ? v0[j] : v1[j - 4];
            float dv = j < 4 ? d0[j] : d1[j - 4];
            float bi = j < 4 ? b0[j] : b1[j - 4];
            float s = sigmoidf_(accv);
            float v = dv * (1.0f + s) - bi;
            vout[j] = v > 0.0f ? v : 0.0f;
        }
        bf16x8 pk;
        #pragma unroll
        for (int j = 0; j < 8; ++j) pk[j] = (short)f32_to_bf16(vout[j]);
        *(bf16x8*)&ca1bf[off] = pk;
        if (writef32) {
            float4 f0 = {vout[0], vout[1], vout[2], vout[3]};
            float4 f1 = {vout[4], vout[5], vout[6], vout[7]};
            *(float4*)&ca1f[off] = f0;
            *(float4*)&ca1f[off + 4] = f1;
        }
    }
}

// gemm2: u = ec5 + ca1@W2 + bias; ec5' = 0.5+0.5*sig(4(u-0.5));
//        ec3' = ec5'*ec3 (+cue if inject) + noise(maskbuf). All state bf16.
__global__ __launch_bounds__(256, 2) void gemm2_kernel(
    const uint16_t* __restrict__ ca1bf, const uint16_t* __restrict__ W2t,
    const float* __restrict__ cue, const float* __restrict__ bias,
    uint16_t* __restrict__ ec3bf, uint16_t* __restrict__ ec5bf,
    const uint64_t* __restrict__ maskstep, int inject)
{
    __shared__ __align__(16) uint16_t SM[2][16384];
    uint16_t* As = SM[0];
    uint16_t* Bs = SM[1];
    f32x16 acc[2][2];
    #pragma unroll
    for (int m = 0; m < 2; ++m)
        #pragma unroll
        for (int n = 0; n < 2; ++n)
            acc[m][n] = (f32x16)(0.0f);

    const int tid = threadIdx.x;
    const int row0 = blockIdx.x * 128, col0 = blockIdx.y * 128;
    const int a = tid & 15;
    const uint64_t mask = maskstep[(size_t)(blockIdx.y * 64 + blockIdx.x) * 256 + tid];

    gemm_core(ca1bf, W2t, As, Bs, acc);

    // T14: issue state loads before acc staging (latency hides under ds traffic)
    bf16x8 e3v[8], e5v[8];
    #pragma unroll
    for (int i = 0; i < 8; ++i) {
        size_t off = (size_t)(row0 + (tid >> 4) + i * 16) * NDIM + col0 + a * 8;
        e3v[i] = *(const bf16x8*)&ec3bf[off];
        e5v[i] = *(const bf16x8*)&ec5bf[off];
    }

    float* lacc = (float*)SM;
    acc_to_lds(lacc, acc);
    __syncthreads();

    int gc = col0 + a * 8;
    float4 b0 = *(const float4*)&bias[gc];
    float4 b1 = *(const float4*)&bias[gc + 4];
    #pragma unroll
    for (int i = 0; i < 8; ++i) {
        int r = (tid >> 4) + i * 16;
        float4 v0, v1;
        acc_read8(lacc, r, a, v0, v1);
        size_t off = (size_t)(row0 + r) * NDIM + gc;
        float4 c0 = {0.f,0.f,0.f,0.f}, c1 = {0.f,0.f,0.f,0.f};
        if (inject) {
            c0 = *(const float4*)&cue[off];
            c1 = *(const float4*)&cue[off + 4];
        }
        bf16x8 p3, p5;
        #pragma unroll
        for (int j = 0; j < 8; ++j) {
            float accv = j < 4 ? v0[j] : v1[j - 4];
            float bi = j < 4 ? b0[j] : b1[j - 4];
            float e5 = bf16_to_f32((uint16_t)e5v[i][j]);
            float e3 = bf16_to_f32((uint16_t)e3v[i][j]);
            float u = e5 + accv + bi;
            float e5n = 0.5f + 0.5f * sigmoidf_(4.0f * (u - 0.5f));
            float e3n = e5n * e3;
            if (inject) e3n += (j < 4 ? c0[j] : c1[j - 4]);
            e3n += ((mask >> (i * 8 + j)) & 1ull) ? 0.2f : 0.0f;
            p5[j] = (short)f32_to_bf16(e5n);
            p3[j] = (short)f32_to_bf16(e3n);
        }
        *(bf16x8*)&ec5bf[off] = p5;
        *(bf16x8*)&ec3bf[off] = p3;
    }
}

// out[b][:2] = ca1[b] @ wca1act + actbias (f64 accumulate, one wave per row)
__global__ __launch_bounds__(256) void final_kernel(
    const float* __restrict__ ca1,
    const float* __restrict__ wact,
    const float* __restrict__ actbias,
    float* __restrict__ out)
{
    int wave = threadIdx.x >> 6, lane = threadIdx.x & 63;
    int b = blockIdx.x * 4 + wave;
    double a0 = 0.0, a1 = 0.0;
    for (int c = lane; c < NDIM; c += 64) {
        double v = (double)ca1[(size_t)b * NDIM + c];
        a0 += v * (double)wact[c * 2 + 0];
        a1 += v * (double)wact[c * 2 + 1];
    }
    #pragma unroll
    for (int off = 32; off > 0; off >>= 1) {
        a0 += __shfl_down(a0, off);
        a1 += __shfl_down(a1, off);
    }
    if (lane == 0) {
        out[(size_t)b * 2 + 0] = (float)(a0 + (double)actbias[0]);
        out[(size_t)b * 2 + 1] = (float)(a1 + (double)actbias[1]);
    }
}

// ---------------- host ----------------
extern "C" void kernel_launch(void* const* d_in, const int* in_sizes, int n_in,
                              void* d_out, int out_size, void* d_ws, size_t ws_size,
                              hipStream_t stream) {
    const float* cue      = (const float*)d_in[0];
    const float* ec5_init = (const float*)d_in[1];
    const float* wca3ca1  = (const float*)d_in[2];
    const float* wec3ca1  = (const float*)d_in[3];
    const float* wca1ec5  = (const float*)d_in[4];
    const float* wca1act  = (const float*)d_in[5];
    const float* ca1bias  = (const float*)d_in[6];
    const float* ec5bias  = (const float*)d_in[7];
    const float* actbias  = (const float*)d_in[8];
    float* out = (float*)d_out;

    const size_t NE = (size_t)BS * NDIM;
    char* p = (char*)d_ws;
    float*    ca1f    = (float*)p;    p += NE * 4;                         // 32 MB
    uint16_t* ec3bf   = (uint16_t*)p; p += NE * 2;                         // 16 MB
    uint16_t* ec5bf   = (uint16_t*)p; p += NE * 2;                         // 16 MB
    uint16_t* ca1bf   = (uint16_t*)p; p += NE * 2;                         // 16 MB
    uint16_t* W1t     = (uint16_t*)p; p += (size_t)NDIM * NDIM * 2;        // 2 MB
    uint16_t* W2t     = (uint16_t*)p; p += (size_t)NDIM * NDIM * 2;        // 2 MB
    uint64_t* maskbuf = (uint64_t*)p; p += (size_t)MASK_CHUNK * SLOTS_PER_STEP * 8; // 21 MB
    float*    drive   = (float*)p;                                          // 0.4 MB

    const int n = (int)NE;
    hipLaunchKernelGGL(init_kernel, dim3((n + 255) / 256), dim3(256), 0, stream,
                       ec5_init, ec3bf, ec5bf, n);
    hipLaunchKernelGGL(drive_kernel, dim3(25, 16), dim3(256), 0, stream,
                       wca3ca1, drive);
    hipLaunchKernelGGL(wtrans_kernel, dim3(32, 32), dim3(256), 0, stream, wec3ca1, W1t);
    hipLaunchKernelGGL(wtrans_kernel, dim3(32, 32), dim3(256), 0, stream, wca1ec5, W2t);

    dim3 blk(256);
    dim3 gg(BS / 128, NDIM / 128);   // (64, 8) = 512 blocks
    for (int t = 0; t < T_STEPS; ++t) {
        if (t < T_STEPS - 1 && (t % MASK_CHUNK) == 0) {
            int nsteps = T_STEPS - 1 - t;            // noise needed for t..98
            if (nsteps > MASK_CHUNK) nsteps = MASK_CHUNK;
            hipLaunchKernelGGL(noise_kernel, dim3(512, nsteps), blk, 0, stream,
                               maskbuf, t);
        }
        hipLaunchKernelGGL(gemm1_kernel, gg, blk, 0, stream,
                           ec3bf, W1t, drive + (size_t)t * NDIM, ca1bias,
                           ca1bf, ca1f, (t == T_STEPS - 1) ? 1 : 0);
        if (t < T_STEPS - 1) {
            hipLaunchKernelGGL(gemm2_kernel, gg, blk, 0, stream,
                               ca1bf, W2t, cue, ec5bias, ec3bf, ec5bf,
                               maskbuf + (size_t)(t % MASK_CHUNK) * SLOTS_PER_STEP,
                               (t == CUE_T) ? 1 : 0);
        }
    }
    hipLaunchKernelGGL(final_kernel, dim3(BS / 4), blk, 0, stream,
                       ca1f, wca1act, actbias, out);
}

// Round 16
// 6175.380 us; speedup vs baseline: 1.0690x; 1.0690x over previous
//
#include <hip/hip_runtime.h>
#include <stdint.h>

#define BS 8192
#define NDIM 1024
#define T_STEPS 100
#define CUE_T 10
#define BK 64
#define NKT (NDIM / BK)

typedef __attribute__((ext_vector_type(8))) short bf16x8;
typedef __attribute__((ext_vector_type(16))) float f32x16;

// ---------------- bf16 helpers (RNE, XLA-compatible) ----------------
__device__ inline uint16_t f32_to_bf16(float f) {
    uint32_t u = __float_as_uint(f);
    uint32_t r = u + 0x7fffu + ((u >> 16) & 1u);
    return (uint16_t)(r >> 16);
}
__device__ inline float bf16_to_f32(uint16_t h) {
    return __uint_as_float(((uint32_t)h) << 16);
}

// ---------------- threefry2x32 (JAX-exact core) ----------------
__host__ __device__ inline uint32_t rotl32_(uint32_t x, uint32_t r) {
    return (x << r) | (x >> (32u - r));
}

__host__ __device__ inline void tf2x32(uint32_t k0, uint32_t k1,
                                       uint32_t x0, uint32_t x1,
                                       uint32_t &o0, uint32_t &o1) {
    uint32_t ks2 = k0 ^ k1 ^ 0x1BD11BDAu;
    x0 += k0; x1 += k1;
#define TF_R4(a,b,c,d) \
    x0 += x1; x1 = rotl32_(x1,(a)); x1 ^= x0; \
    x0 += x1; x1 = rotl32_(x1,(b)); x1 ^= x0; \
    x0 += x1; x1 = rotl32_(x1,(c)); x1 ^= x0; \
    x0 += x1; x1 = rotl32_(x1,(d)); x1 ^= x0;
    TF_R4(13,15,26,6)  x0 += k1;  x1 += ks2 + 1u;
    TF_R4(17,29,16,24) x0 += ks2; x1 += k0 + 2u;
    TF_R4(13,15,26,6)  x0 += k0;  x1 += k1 + 3u;
    TF_R4(17,29,16,24) x0 += k1;  x1 += ks2 + 4u;
    TF_R4(13,15,26,6)  x0 += ks2; x1 += k0 + 5u;
#undef TF_R4
    o0 = x0; o1 = x1;
}

// 4-wide interleaved threefry: 4 independent chains round-interleaved for ILP.
// counters (0, idx[i]); returns XOR-folded bits[i] = o0^o1 (JAX partitionable).
__device__ __forceinline__ void tf2x32_x4_fold(uint32_t k0, uint32_t k1,
                                               const uint32_t idx[4],
                                               uint32_t bits[4]) {
    uint32_t ks2 = k0 ^ k1 ^ 0x1BD11BDAu;
    uint32_t x0[4], x1[4];
    #pragma unroll
    for (int i = 0; i < 4; ++i) { x0[i] = k0; x1[i] = idx[i] + k1; }
#define TF4_R(rot) \
    _Pragma("unroll") \
    for (int i = 0; i < 4; ++i) { \
        x0[i] += x1[i]; x1[i] = rotl32_(x1[i], (rot)); x1[i] ^= x0[i]; }
#define TF4_K(a0, a1) \
    _Pragma("unroll") \
    for (int i = 0; i < 4; ++i) { x0[i] += (a0); x1[i] += (a1); }
    TF4_R(13) TF4_R(15) TF4_R(26) TF4_R(6)  TF4_K(k1, ks2 + 1u)
    TF4_R(17) TF4_R(29) TF4_R(16) TF4_R(24) TF4_K(ks2, k0 + 2u)
    TF4_R(13) TF4_R(15) TF4_R(26) TF4_R(6)  TF4_K(k0, k1 + 3u)
    TF4_R(17) TF4_R(29) TF4_R(16) TF4_R(24) TF4_K(k1, ks2 + 4u)
    TF4_R(13) TF4_R(15) TF4_R(26) TF4_R(6)  TF4_K(ks2, k0 + 5u)
#undef TF4_R
#undef TF4_K
    #pragma unroll
    for (int i = 0; i < 4; ++i) bits[i] = x0[i] ^ x1[i];
}

// fast sigmoid: v_exp_f32 + v_rcp_f32 (rel err ~1e-6, invisible under bf16)
__device__ inline float sigmoidf_(float x) {
    float e = __expf(-x);
    return __builtin_amdgcn_rcpf(1.0f + e);
}

// ---------------- async global->LDS, 16B per lane ----------------
__device__ __forceinline__ void gload16(const uint16_t* g, uint16_t* l) {
    __builtin_amdgcn_global_load_lds(
        (const __attribute__((address_space(1))) void*)g,
        (__attribute__((address_space(3))) void*)l, 16, 0, 0);
}

// ---------------- init: ec3bf = 0, ec5bf = bf16(ec5_init) ----------------
__global__ void init_kernel(const float* __restrict__ ec5_init,
                            uint16_t* __restrict__ ec3bf,
                            uint16_t* __restrict__ ec5bf, int n) {
    int i = blockIdx.x * blockDim.x + threadIdx.x;
    if (i < n) { ec3bf[i] = 0; ec5bf[i] = f32_to_bf16(ec5_init[i]); }
}

// ---------------- drive[t][c] = sum_j exp(-(cen_j - t)^2/50) * W[j][c] ----------------
__global__ __launch_bounds__(256) void drive_kernel(const float* __restrict__ W,
                                                    float* __restrict__ drive) {
    __shared__ float g[4][1024];
    const int t0 = blockIdx.x * 4;
    const int c = blockIdx.y * 64 + (threadIdx.x & 63);
    const int tt = threadIdx.x >> 6;
    const float stepf = 100.0f / 1023.0f;
    for (int i = threadIdx.x; i < 4096; i += 256) {
        int t_ = i >> 10, j = i & 1023;
        float d = stepf * (float)j - (float)(t0 + t_);
        g[t_][j] = expf(-(d * d) * 0.02f);
    }
    __syncthreads();
    float a = 0.f;
    for (int j = 0; j < 1024; ++j)
        a = fmaf(g[tt][j], W[(size_t)j * NDIM + c], a);
    drive[(size_t)(t0 + tt) * NDIM + c] = a;
}

// ---------------- Wt_bf16[n][k] = bf16(W[k][n]), runs once ----------------
__global__ __launch_bounds__(256) void wtrans_kernel(const float* __restrict__ W,
                                                     uint16_t* __restrict__ Wt) {
    __shared__ float tile[32][33];
    int k0 = blockIdx.x * 32, n0 = blockIdx.y * 32;
    int tx = threadIdx.x & 31, ty = threadIdx.x >> 5;
    #pragma unroll
    for (int i = 0; i < 32; i += 8)
        tile[ty + i][tx] = W[(size_t)(k0 + ty + i) * NDIM + n0 + tx];
    __syncthreads();
    #pragma unroll
    for (int i = 0; i < 32; i += 8)
        Wt[(size_t)(n0 + ty + i) * NDIM + k0 + tx] = f32_to_bf16(tile[tx][ty + i]);
}

// Stage acc (MFMA C-layout) into LDS with chunk-XOR swizzle; coalesced re-read.
__device__ __forceinline__ void acc_to_lds(float* lacc, f32x16 acc[2][2]) {
    const int tid = threadIdx.x, wid = tid >> 6, lane = tid & 63;
    const int wr = wid >> 1, wc = wid & 1, l31 = lane & 31, l5 = lane >> 5;
    #pragma unroll
    for (int m = 0; m < 2; ++m)
        #pragma unroll
        for (int n = 0; n < 2; ++n) {
            int c = wc * 64 + n * 32 + l31;
            int chunk = c >> 2, cj = c & 3;
            #pragma unroll
            for (int e = 0; e < 16; ++e) {
                int r = wr * 64 + m * 32 + (e & 3) + ((e >> 2) << 3) + (l5 << 2);
                lacc[r * 128 + ((chunk ^ (r & 31)) << 2) + cj] = acc[m][n][e];
            }
        }
}

__device__ __forceinline__ void acc_read8(const float* lacc, int r, int a,
                                          float4 &v0, float4 &v1) {
    int rb = r & 31;
    v0 = *(const float4*)&lacc[r * 128 + ((((a << 1) | 0) ^ rb) << 2)];
    v1 = *(const float4*)&lacc[r * 128 + ((((a << 1) | 1) ^ rb) << 2)];
}

// gemm1: 512 threads = 4 GEMM waves (wid 0-3, 128x128 tile, dbuf+counted vmcnt)
//        + 4 noise waves (wid 4-7, threefry for this step's gemm2 mask).
// Noise waves run between the SAME barriers; their VALU work co-issues against
// the GEMM waves' MFMA/LDS pipes (m114). Mask bit-layout = R13 (verified):
// noise thread nt covers consumer-thread nt's 64 elements; per kt, 4 bits
// e=4kt..4kt+3, element off = obase + (e>>3)*16384 + (e&7).
__global__ __launch_bounds__(512, 4) void gemm1_kernel(
    const uint16_t* __restrict__ ec3bf, const uint16_t* __restrict__ W1t,
    const float* __restrict__ drv, const float* __restrict__ bias,
    uint16_t* __restrict__ ca1bf, float* __restrict__ ca1f, int writef32,
    uint64_t* __restrict__ maskbuf, uint32_t k0_, uint32_t k1_)
{
    __shared__ __align__(16) uint16_t SM[2][16384];   // 64 KB
    uint16_t* As = SM[0];
    uint16_t* Bs = SM[1];
    const int tid = threadIdx.x;
    const int wid = tid >> 6, lane = tid & 63;
    const bool gw = wid < 4;                          // GEMM wave?
    const int row0 = blockIdx.x * 128, col0 = blockIdx.y * 128;

    f32x16 acc[2][2];
    #pragma unroll
    for (int m = 0; m < 2; ++m)
        #pragma unroll
        for (int n = 0; n < 2; ++n)
            acc[m][n] = (f32x16)(0.0f);

    // ---- GEMM-wave setup (valid for wid 0-3) ----
    const int srow = lane >> 3;
    const int soff = ((lane & 7) ^ srow) * 8;
    const int gwid = wid & 3;
    const uint16_t* aS[4]; const uint16_t* bS[4];
    #pragma unroll
    for (int i = 0; i < 4; ++i) {
        int ch = gwid * 4 + i;
        aS[i] = ec3bf + (size_t)(row0 + ch * 8 + srow) * NDIM + soff;
        bS[i] = W1t   + (size_t)(col0 + ch * 8 + srow) * NDIM + soff;
    }
    const int l31 = lane & 31, l5 = lane >> 5;
    const int wr = gwid >> 1, wc = gwid & 1;
    int aoff[2][4], boff[2][4];
    #pragma unroll
    for (int m = 0; m < 2; ++m)
        #pragma unroll
        for (int kk = 0; kk < 4; ++kk) {
            int ar = wr * 64 + m * 32 + l31;
            aoff[m][kk] = ar * BK + ((((kk << 1) | l5) ^ (ar & 7)) << 3);
            int br = wc * 64 + m * 32 + l31;
            boff[m][kk] = br * BK + ((((kk << 1) | l5) ^ (br & 7)) << 3);
        }

    // ---- noise-wave setup (valid for wid 4-7) ----
    const int nt = tid & 255;   // consumer thread id in gemm2's 256-thread block
    const uint32_t obase = (uint32_t)(row0 + (nt >> 4)) * NDIM
                         + (uint32_t)(col0 + (nt & 15) * 8);
    uint64_t mask = 0;

    if (gw) {
        #pragma unroll
        for (int i = 0; i < 4; ++i) {
            int ch = gwid * 4 + i;
            gload16(aS[i], As + ch * 512);
            gload16(bS[i], Bs + ch * 512);
        }
    }

    for (int kt = 0; kt < NKT; ++kt) {
        const int cur = kt & 1;
        if (gw) {
            if (kt + 1 < NKT) {
                const int nb = (cur ^ 1) * 8192;
                const int k0n = (kt + 1) * BK;
                #pragma unroll
                for (int i = 0; i < 4; ++i) {
                    int ch = gwid * 4 + i;
                    gload16(aS[i] + k0n, As + nb + ch * 512);
                    gload16(bS[i] + k0n, Bs + nb + ch * 512);
                }
                asm volatile("s_waitcnt vmcnt(8)" ::: "memory");
            } else {
                asm volatile("s_waitcnt vmcnt(0)" ::: "memory");
            }
        }
        __builtin_amdgcn_s_barrier();
        __builtin_amdgcn_sched_barrier(0);
        if (gw) {
            const uint16_t* as = As + cur * 8192;
            const uint16_t* bs = Bs + cur * 8192;
            bf16x8 af[2][4], bfr[2][4];
            #pragma unroll
            for (int m = 0; m < 2; ++m)
                #pragma unroll
                for (int kk = 0; kk < 4; ++kk) {
                    af[m][kk]  = *(const bf16x8*)&as[aoff[m][kk]];
                    bfr[m][kk] = *(const bf16x8*)&bs[boff[m][kk]];
                }
            #pragma unroll
            for (int kk = 0; kk < 4; ++kk)
                #pragma unroll
                for (int m = 0; m < 2; ++m)
                    #pragma unroll
                    for (int n = 0; n < 2; ++n)
                        acc[m][n] = __builtin_amdgcn_mfma_f32_32x32x16_bf16(
                            af[m][kk], bfr[n][kk], acc[m][n], 0, 0, 0);
        } else {
            // 4 bernoulli bits for elements e = 4kt .. 4kt+3 (dedicated VALU)
            uint32_t idx[4], bits[4];
            const uint32_t base = obase + (uint32_t)((kt >> 1) << 14)
                                + (uint32_t)((kt & 1) << 2);
            #pragma unroll
            for (int u = 0; u < 4; ++u) idx[u] = base + u;
            tf2x32_x4_fold(k0_, k1_, idx, bits);
            #pragma unroll
            for (int u = 0; u < 4; ++u) {
                float uu = __uint_as_float((bits[u] >> 9) | 0x3f800000u) - 1.0f;
                mask |= (uint64_t)(uu < 0.004f ? 1u : 0u) << ((kt << 2) + u);
            }
        }
        __builtin_amdgcn_sched_barrier(0);
        __builtin_amdgcn_s_barrier();
    }

    if (!gw)
        maskbuf[(size_t)(blockIdx.y * 64 + blockIdx.x) * 256 + nt] = mask;

    float* lacc = (float*)SM;
    if (gw) acc_to_lds(lacc, acc);
    __syncthreads();

    // epilogue: all 512 threads, 4 rows x 8 cols each
    const int a = tid & 15;
    int gc = col0 + a * 8;
    float4 d0 = *(const float4*)&drv[gc];
    float4 d1 = *(const float4*)&drv[gc + 4];
    float4 b0 = *(const float4*)&bias[gc];
    float4 b1 = *(const float4*)&bias[gc + 4];
    #pragma unroll
    for (int i = 0; i < 4; ++i) {
        int r = (tid >> 4) + i * 32;
        float4 v0, v1;
        acc_read8(lacc, r, a, v0, v1);
        size_t off = (size_t)(row0 + r) * NDIM + gc;
        float vout[8];
        #pragma unroll
        for (int j = 0; j < 8; ++j) {
            float accv = j < 4 ? v0[j] : v1[j - 4];
            float dv = j < 4 ? d0[j] : d1[j - 4];
            float bi = j < 4 ? b0[j] : b1[j - 4];
            float s = sigmoidf_(accv);
            float v = dv * (1.0f + s) - bi;
            vout[j] = v > 0.0f ? v : 0.0f;
        }
        bf16x8 pk;
        #pragma unroll
        for (int j = 0; j < 8; ++j) pk[j] = (short)f32_to_bf16(vout[j]);
        *(bf16x8*)&ca1bf[off] = pk;
        if (writef32) {
            float4 f0 = {vout[0], vout[1], vout[2], vout[3]};
            float4 f1 = {vout[4], vout[5], vout[6], vout[7]};
            *(float4*)&ca1f[off] = f0;
            *(float4*)&ca1f[off + 4] = f1;
        }
    }
}

// ---------------- gemm_core for gemm2 (256 threads, unchanged) ----------------
__device__ __forceinline__ void gemm_core(const uint16_t* __restrict__ A,
                                          const uint16_t* __restrict__ Bt,
                                          uint16_t* As, uint16_t* Bs,
                                          f32x16 acc[2][2]) {
    const int tid = threadIdx.x;
    const int wid = tid >> 6, lane = tid & 63;
    const int row0 = blockIdx.x * 128, col0 = blockIdx.y * 128;
    const int srow = lane >> 3;
    const int soff = ((lane & 7) ^ srow) * 8;
    const uint16_t* aS[4]; const uint16_t* bS[4];
    #pragma unroll
    for (int i = 0; i < 4; ++i) {
        int ch = wid * 4 + i;
        aS[i] = A  + (size_t)(row0 + ch * 8 + srow) * NDIM + soff;
        bS[i] = Bt + (size_t)(col0 + ch * 8 + srow) * NDIM + soff;
    }
    const int l31 = lane & 31, l5 = lane >> 5;
    const int wr = wid >> 1, wc = wid & 1;
    int aoff[2][4], boff[2][4];
    #pragma unroll
    for (int m = 0; m < 2; ++m)
        #pragma unroll
        for (int kk = 0; kk < 4; ++kk) {
            int ar = wr * 64 + m * 32 + l31;
            aoff[m][kk] = ar * BK + ((((kk << 1) | l5) ^ (ar & 7)) << 3);
            int br = wc * 64 + m * 32 + l31;
            boff[m][kk] = br * BK + ((((kk << 1) | l5) ^ (br & 7)) << 3);
        }

    #pragma unroll
    for (int i = 0; i < 4; ++i) {
        int ch = wid * 4 + i;
        gload16(aS[i], As + ch * 512);
        gload16(bS[i], Bs + ch * 512);
    }

    for (int kt = 0; kt < NKT; ++kt) {
        const int cur = kt & 1;
        if (kt + 1 < NKT) {
            const int nb = (cur ^ 1) * 8192;
            const int k0n = (kt + 1) * BK;
            #pragma unroll
            for (int i = 0; i < 4; ++i) {
                int ch = wid * 4 + i;
                gload16(aS[i] + k0n, As + nb + ch * 512);
                gload16(bS[i] + k0n, Bs + nb + ch * 512);
            }
            asm volatile("s_waitcnt vmcnt(8)" ::: "memory");
        } else {
            asm volatile("s_waitcnt vmcnt(0)" ::: "memory");
        }
        __builtin_amdgcn_s_barrier();
        __builtin_amdgcn_sched_barrier(0);
        const uint16_t* as = As + cur * 8192;
        const uint16_t* bs = Bs + cur * 8192;
        bf16x8 af[2][4], bfr[2][4];
        #pragma unroll
        for (int m = 0; m < 2; ++m)
            #pragma unroll
            for (int kk = 0; kk < 4; ++kk) {
                af[m][kk]  = *(const bf16x8*)&as[aoff[m][kk]];
                bfr[m][kk] = *(const bf16x8*)&bs[boff[m][kk]];
            }
        #pragma unroll
        for (int kk = 0; kk < 4; ++kk)
            #pragma unroll
            for (int m = 0; m < 2; ++m)
                #pragma unroll
                for (int n = 0; n < 2; ++n)
                    acc[m][n] = __builtin_amdgcn_mfma_f32_32x32x16_bf16(
                        af[m][kk], bfr[n][kk], acc[m][n], 0, 0, 0);
        __builtin_amdgcn_sched_barrier(0);
        __builtin_amdgcn_s_barrier();
    }
}

// gemm2: u = ec5 + ca1@W2 + bias; ec5' = 0.5+0.5*sig(4(u-0.5));
//        ec3' = ec5'*ec3 (+cue if inject) + noise(maskbuf). All state bf16.
__global__ __launch_bounds__(256, 2) void gemm2_kernel(
    const uint16_t* __restrict__ ca1bf, const uint16_t* __restrict__ W2t,
    const float* __restrict__ cue, const float* __restrict__ bias,
    uint16_t* __restrict__ ec3bf, uint16_t* __restrict__ ec5bf,
    const uint64_t* __restrict__ maskbuf, int inject)
{
    __shared__ __align__(16) uint16_t SM[2][16384];
    uint16_t* As = SM[0];
    uint16_t* Bs = SM[1];
    f32x16 acc[2][2];
    #pragma unroll
    for (int m = 0; m < 2; ++m)
        #pragma unroll
        for (int n = 0; n < 2; ++n)
            acc[m][n] = (f32x16)(0.0f);

    const int tid = threadIdx.x;
    const int row0 = blockIdx.x * 128, col0 = blockIdx.y * 128;
    const int a = tid & 15;
    const uint64_t mask = maskbuf[(size_t)(blockIdx.y * 64 + blockIdx.x) * 256 + tid];

    gemm_core(ca1bf, W2t, As, Bs, acc);

    // T14: issue state loads before acc staging (latency hides under ds traffic)
    bf16x8 e3v[8], e5v[8];
    #pragma unroll
    for (int i = 0; i < 8; ++i) {
        size_t off = (size_t)(row0 + (tid >> 4) + i * 16) * NDIM + col0 + a * 8;
        e3v[i] = *(const bf16x8*)&ec3bf[off];
        e5v[i] = *(const bf16x8*)&ec5bf[off];
    }

    float* lacc = (float*)SM;
    acc_to_lds(lacc, acc);
    __syncthreads();

    int gc = col0 + a * 8;
    float4 b0 = *(const float4*)&bias[gc];
    float4 b1 = *(const float4*)&bias[gc + 4];
    #pragma unroll
    for (int i = 0; i < 8; ++i) {
        int r = (tid >> 4) + i * 16;
        float4 v0, v1;
        acc_read8(lacc, r, a, v0, v1);
        size_t off = (size_t)(row0 + r) * NDIM + gc;
        float4 c0 = {0.f,0.f,0.f,0.f}, c1 = {0.f,0.f,0.f,0.f};
        if (inject) {
            c0 = *(const float4*)&cue[off];
            c1 = *(const float4*)&cue[off + 4];
        }
        bf16x8 p3, p5;
        #pragma unroll
        for (int j = 0; j < 8; ++j) {
            float accv = j < 4 ? v0[j] : v1[j - 4];
            float bi = j < 4 ? b0[j] : b1[j - 4];
            float e5 = bf16_to_f32((uint16_t)e5v[i][j]);
            float e3 = bf16_to_f32((uint16_t)e3v[i][j]);
            float u = e5 + accv + bi;
            float e5n = 0.5f + 0.5f * sigmoidf_(4.0f * (u - 0.5f));
            float e3n = e5n * e3;
            if (inject) e3n += (j < 4 ? c0[j] : c1[j - 4]);
            e3n += ((mask >> (i * 8 + j)) & 1ull) ? 0.2f : 0.0f;
            p5[j] = (short)f32_to_bf16(e5n);
            p3[j] = (short)f32_to_bf16(e3n);
        }
        *(bf16x8*)&ec5bf[off] = p5;
        *(bf16x8*)&ec3bf[off] = p3;
    }
}

// out[b][:2] = ca1[b] @ wca1act + actbias (f64 accumulate, one wave per row)
__global__ __launch_bounds__(256) void final_kernel(
    const float* __restrict__ ca1,
    const float* __restrict__ wact,
    const float* __restrict__ actbias,
    float* __restrict__ out)
{
    int wave = threadIdx.x >> 6, lane = threadIdx.x & 63;
    int b = blockIdx.x * 4 + wave;
    double a0 = 0.0, a1 = 0.0;
    for (int c = lane; c < NDIM; c += 64) {
        double v = (double)ca1[(size_t)b * NDIM + c];
        a0 += v * (double)wact[c * 2 + 0];
        a1 += v * (double)wact[c * 2 + 1];
    }
    #pragma unroll
    for (int off = 32; off > 0; off >>= 1) {
        a0 += __shfl_down(a0, off);
        a1 += __shfl_down(a1, off);
    }
    if (lane == 0) {
        out[(size_t)b * 2 + 0] = (float)(a0 + (double)actbias[0]);
        out[(size_t)b * 2 + 1] = (float)(a1 + (double)actbias[1]);
    }
}

// ---------------- host ----------------
extern "C" void kernel_launch(void* const* d_in, const int* in_sizes, int n_in,
                              void* d_out, int out_size, void* d_ws, size_t ws_size,
                              hipStream_t stream) {
    const float* cue      = (const float*)d_in[0];
    const float* ec5_init = (const float*)d_in[1];
    const float* wca3ca1  = (const float*)d_in[2];
    const float* wec3ca1  = (const float*)d_in[3];
    const float* wca1ec5  = (const float*)d_in[4];
    const float* wca1act  = (const float*)d_in[5];
    const float* ca1bias  = (const float*)d_in[6];
    const float* ec5bias  = (const float*)d_in[7];
    const float* actbias  = (const float*)d_in[8];
    float* out = (float*)d_out;

    const size_t NE = (size_t)BS * NDIM;
    char* p = (char*)d_ws;
    float*    ca1f    = (float*)p;    p += NE * 4;                  // 32 MB
    uint16_t* ec3bf   = (uint16_t*)p; p += NE * 2;                  // 16 MB
    uint16_t* ec5bf   = (uint16_t*)p; p += NE * 2;                  // 16 MB
    uint16_t* ca1bf   = (uint16_t*)p; p += NE * 2;                  // 16 MB
    uint16_t* W1t     = (uint16_t*)p; p += (size_t)NDIM * NDIM * 2; // 2 MB
    uint16_t* W2t     = (uint16_t*)p; p += (size_t)NDIM * NDIM * 2; // 2 MB
    uint64_t* maskbuf = (uint64_t*)p; p += (size_t)512 * 256 * 8;   // 1 MB
    float*    drive   = (float*)p;                                   // 0.4 MB

    const int n = (int)NE;
    hipLaunchKernelGGL(init_kernel, dim3((n + 255) / 256), dim3(256), 0, stream,
                       ec5_init, ec3bf, ec5bf, n);
    hipLaunchKernelGGL(drive_kernel, dim3(25, 16), dim3(256), 0, stream,
                       wca3ca1, drive);
    hipLaunchKernelGGL(wtrans_kernel, dim3(32, 32), dim3(256), 0, stream, wec3ca1, W1t);
    hipLaunchKernelGGL(wtrans_kernel, dim3(32, 32), dim3(256), 0, stream, wca1ec5, W2t);

    dim3 gg(BS / 128, NDIM / 128);   // (64, 8) = 512 blocks
    for (int t = 0; t < T_STEPS; ++t) {
        uint32_t k0, k1;
        tf2x32(0u, 42u, 0u, (uint32_t)t, k0, k1);   // fold_in(key(42), t)
        hipLaunchKernelGGL(gemm1_kernel, gg, dim3(512), 0, stream,
                           ec3bf, W1t, drive + (size_t)t * NDIM, ca1bias,
                           ca1bf, ca1f, (t == T_STEPS - 1) ? 1 : 0,
                           maskbuf, k0, k1);
        if (t < T_STEPS - 1) {
            hipLaunchKernelGGL(gemm2_kernel, gg, dim3(256), 0, stream,
                               ca1bf, W2t, cue, ec5bias, ec3bf, ec5bf,
                               maskbuf, (t == CUE_T) ? 1 : 0);
        }
    }
    hipLaunchKernelGGL(final_kernel, dim3(BS / 4), dim3(256), 0, stream,
                       ca1f, wca1act, actbias, out);
}